// Round 1
// baseline (328.105 us; speedup 1.0000x reference)
//
#include <hip/hip_runtime.h>
#include <math.h>

typedef float f32x4 __attribute__((ext_vector_type(4)));
typedef short bf16x8 __attribute__((ext_vector_type(8)));
typedef _Float16 f16x8 __attribute__((ext_vector_type(8)));
typedef _Float16 f16x4 __attribute__((ext_vector_type(4)));

#define D 64
#define TT 8
#define RR 8

#define SCAN_TPB 256
#define SCAN_CH 4
#define SCAN_ELEMS (SCAN_TPB * SCAN_CH)   // 1024 elements per block

#define HIST_CH 8                          // edges per thread (outstanding atomics)
#define SCAT_CH 4
#define SCORE_XB 256                       // score x-blocks (x4 waves = 1024 wave slots)
#define V2_XB 64                           // v2 x-blocks (x4 waves = 256 wave slots, stride 256)
#define AGG_XB 256                         // agg_out x-blocks per type

// dst-block size for (relation, dst>>6) bucketing of the relation-sorted edge list.
// 64 dst rows = 8KB of qn -> q gathers + rec scatters confined to an L1/L2-resident window.
#define DBSHIFT 6

// ---------------- scalar helpers ----------------
__device__ __forceinline__ float bf2f(unsigned short u) {
    union { unsigned int i; float f; } x;
    x.i = ((unsigned int)u) << 16;
    return x.f;
}
__device__ __forceinline__ unsigned short f2bf(float f) {
    union { float f; unsigned int i; } x;
    x.f = f;
    unsigned int i = x.i;
    unsigned int r = (i + 0x7FFFu + ((i >> 16) & 1u)) >> 16;   // RNE
    return (unsigned short)r;
}
struct BfPair { short hi; short lo; };
__device__ __forceinline__ BfPair split2(float x) {
    BfPair p;
    unsigned short h = f2bf(x);
    p.hi = (short)h;
    p.lo = (short)f2bf(x - bf2f(h));
    return p;
}
__device__ __forceinline__ void load_A_split(const float* __restrict__ p, bf16x8& ah, bf16x8& al) {
#pragma unroll
    for (int i = 0; i < 8; ++i) {
        BfPair s = split2(p[i]);
        ah[i] = s.hi; al[i] = s.lo;
    }
}
// bf16 split B fragment (used by proj/out split GEMMs)
__device__ __forceinline__ void load_B_split(const float* __restrict__ W, int ks, int c, int lane,
                                             bf16x8& bh, bf16x8& bl) {
    int n = lane & 15, q = lane >> 4;
#pragma unroll
    for (int i = 0; i < 8; ++i) {
        BfPair s = split2(W[(ks * 32 + q * 8 + i) * 64 + c * 16 + n]);
        bh[i] = s.hi; bl[i] = s.lo;
    }
}
// fp16 split B fragment (score: A-matrix hi+lo)
__device__ __forceinline__ void load_B_split_f16(const float* __restrict__ W, int ks, int c, int lane,
                                                 f16x8& bh, f16x8& bl) {
    int n = lane & 15, q = lane >> 4;
#pragma unroll
    for (int i = 0; i < 8; ++i) {
        float w = W[(ks * 32 + q * 8 + i) * 64 + c * 16 + n];
        _Float16 h = (_Float16)w;
        bh[i] = h;
        bl[i] = (_Float16)(w - (float)h);
    }
}
// fp16 single B fragment (V2 build)
__device__ __forceinline__ f16x8 load_B_frag_f16(const float* __restrict__ W, int ks, int c, int lane) {
    int n = lane & 15, q = lane >> 4;
    f16x8 r;
#pragma unroll
    for (int i = 0; i < 8; ++i)
        r[i] = (_Float16)W[(ks * 32 + q * 8 + i) * 64 + c * 16 + n];
    return r;
}

#define MFMA16(a, b, c) __builtin_amdgcn_mfma_f32_16x16x32_bf16(a, b, c, 0, 0, 0)
#define MFMAH(a, b, c)  __builtin_amdgcn_mfma_f32_16x16x32_f16(a, b, c, 0, 0, 0)

// 24 bf16 MFMAs: acc += (Ah+Al)@(Bh+Bl) dropping lo*lo
#define SPLIT_MFMA_BODY(acc, A0h, A0l, A1h, A1l, Bh, Bl)          \
    _Pragma("unroll")                                             \
    for (int c = 0; c < 4; ++c) {                                 \
        acc[c] = MFMA16(A0h, Bh[0][c], acc[c]);                   \
        acc[c] = MFMA16(A0l, Bh[0][c], acc[c]);                   \
        acc[c] = MFMA16(A0h, Bl[0][c], acc[c]);                   \
        acc[c] = MFMA16(A1h, Bh[1][c], acc[c]);                   \
        acc[c] = MFMA16(A1l, Bh[1][c], acc[c]);                   \
        acc[c] = MFMA16(A1h, Bl[1][c], acc[c]);                   \
    }

// ---------------- CSR build ----------------
// degb = [ deg[N] | bcnt[RR*NBR] ] -- both histogrammed here, scanned together.
__global__ void hist_kernel(const int* __restrict__ dst, const int* __restrict__ et,
                            const int* __restrict__ nt,
                            int* __restrict__ degb, int* __restrict__ tcnt,
                            int* __restrict__ erank, int N, int E, int NBR) {
    __shared__ int l_t[TT];
    if (threadIdx.x < TT) l_t[threadIdx.x] = 0;
    __syncthreads();
    const int stride = gridDim.x * blockDim.x;
    const int tid = blockIdx.x * blockDim.x + threadIdx.x;
#pragma unroll
    for (int i = 0; i < HIST_CH; ++i) {
        int e = tid + i * stride;
        if (e < E) {
            int d = dst[e];
            erank[e] = atomicAdd(&degb[d], 1);
            atomicAdd(&degb[N + et[e] * NBR + (d >> DBSHIFT)], 1);  // non-returning
        }
    }
#pragma unroll
    for (int i = 0; i < HIST_CH; ++i) {
        int n = tid + i * stride;
        if (n < N) atomicAdd(&l_t[nt[n]], 1);
    }
    __syncthreads();
    if (threadIdx.x < TT && l_t[threadIdx.x]) atomicAdd(&tcnt[threadIdx.x], l_t[threadIdx.x]);
}

// ---- 2-phase device-wide exclusive scan of degb[0..Nscan) ----
__global__ void scan_sum_kernel(const int* __restrict__ deg, int* __restrict__ bsum, int N) {
    __shared__ int ws[SCAN_TPB / 64];
    int tid = threadIdx.x;
    int base = blockIdx.x * SCAN_ELEMS + tid * SCAN_CH;
    int s = 0;
#pragma unroll
    for (int i = 0; i < SCAN_CH; ++i) {
        int idx = base + i;
        if (idx < N) s += deg[idx];
    }
#pragma unroll
    for (int d = 32; d; d >>= 1) s += __shfl_xor(s, d, 64);
    if ((tid & 63) == 0) ws[tid >> 6] = s;
    __syncthreads();
    if (tid == 0) {
        int t = 0;
#pragma unroll
        for (int i = 0; i < SCAN_TPB / 64; ++i) t += ws[i];
        bsum[blockIdx.x] = t;
    }
}
// scan_out: per-block base via wave prefix of bsum; block 0 writes toff/tcur.
// N here = Nscan (nodes + buckets); Etot = 2E (deg sums to E, bcnt sums to E).
__global__ void scan_out_kernel(const int* __restrict__ deg, const int* __restrict__ bsum, int nsb,
                                int* __restrict__ off, int N, int Etot,
                                const int* __restrict__ tcnt, int* __restrict__ toff, int* __restrict__ tcur) {
    __shared__ int ts[SCAN_TPB];
    __shared__ int bb;
    int tid = threadIdx.x;
    if (tid < 64) {
        int v = 0;
        if (nsb <= 64) {
            v = (tid < nsb && tid < blockIdx.x) ? bsum[tid] : 0;
#pragma unroll
            for (int d = 32; d; d >>= 1) v += __shfl_xor(v, d, 64);
        } else if (tid == 0) {
            for (int b = 0; b < blockIdx.x; ++b) v += bsum[b];
        }
        if (tid == 0) bb = v;
    }
    if (blockIdx.x == 0 && tid == 1) {
        int a = 0;
        for (int t = 0; t < TT; ++t) { toff[t] = a; tcur[t] = a; a += tcnt[t]; }
        toff[TT] = a;
        off[N] = Etot;
    }
    int base = blockIdx.x * SCAN_ELEMS + tid * SCAN_CH;
    int loc[SCAN_CH];
    int s = 0;
#pragma unroll
    for (int i = 0; i < SCAN_CH; ++i) {
        int idx = base + i;
        int v = (idx < N) ? deg[idx] : 0;
        loc[i] = v; s += v;
    }
    ts[tid] = s;
    __syncthreads();
    for (int sh = 1; sh < SCAN_TPB; sh <<= 1) {
        int v = (tid >= sh) ? ts[tid - sh] : 0;
        __syncthreads();
        ts[tid] += v;
        __syncthreads();
    }
    int run = bb + ((tid > 0) ? ts[tid - 1] : 0);
#pragma unroll
    for (int i = 0; i < SCAN_CH; ++i) {
        int idx = base + i;
        if (idx < N) { off[idx] = run; run += loc[i]; }
    }
}

// scatter: CSR pos = offs[d] + erank[e] (unchanged); relation-sorted slot via
// (r, dst>>6) bucket base + per-bucket atomic rank -> q gathers & rec writes localized.
__global__ void scatter_kernel(const int* __restrict__ src, const int* __restrict__ dst,
                               const int* __restrict__ et, const int* __restrict__ nt,
                               const int* __restrict__ offs, const int* __restrict__ erank,
                               int* __restrict__ tcur, int* __restrict__ bcur,
                               int* __restrict__ rsrc, int* __restrict__ rdst,
                               int* __restrict__ rdpos, int* __restrict__ nidx,
                               int N, int E, int NBR) {
    __shared__ int l_t[TT], base_t[TT];
    if (threadIdx.x < TT) l_t[threadIdx.x] = 0;
    __syncthreads();
    const int stride = gridDim.x * blockDim.x;
    const int tid = blockIdx.x * blockDim.x + threadIdx.x;
    int s[SCAT_CH], d[SCAT_CH], r[SCAT_CH];
    int t[SCAT_CH], trank[SCAT_CH];
#pragma unroll
    for (int i = 0; i < SCAT_CH; ++i) {
        int e = tid + i * stride;
        if (e < E) {
            s[i] = src[e]; d[i] = dst[e]; r[i] = et[e];
        }
        int n = tid + i * stride;
        if (n < N) {
            t[i] = nt[n];
            trank[i] = atomicAdd(&l_t[t[i]], 1);
        }
    }
    __syncthreads();
    if (threadIdx.x < TT)
        base_t[threadIdx.x] = l_t[threadIdx.x] ? atomicAdd(&tcur[threadIdx.x], l_t[threadIdx.x]) : 0;
    __syncthreads();
#pragma unroll
    for (int i = 0; i < SCAT_CH; ++i) {
        int e = tid + i * stride;
        if (e < E) {
            int bucket = r[i] * NBR + (d[i] >> DBSHIFT);
            int rp = (offs[N + bucket] - E) + atomicAdd(&bcur[bucket], 1);
            int pos = offs[d[i]] + erank[e];
            rsrc[rp] = s[i]; rdst[rp] = d[i]; rdpos[rp] = pos;
        }
        int n = tid + i * stride;
        if (n < N) nidx[base_t[t[i]] + trank[i]] = n;
    }
}

// ---------------- node projections ----------------
// a=0: k -> fp16 row (128B); a=1: q -> fp16 row (128B); a=2: v fp16.
__global__ void proj_kernel(const float* __restrict__ h,
                            const float* __restrict__ Wk, const float* __restrict__ Wq,
                            const float* __restrict__ Wv,
                            const int* __restrict__ toff, const int* __restrict__ nidx,
                            _Float16* __restrict__ kh16,
                            _Float16* __restrict__ qout, _Float16* __restrict__ vout) {
    const int t = blockIdx.z, a = blockIdx.y, lane = threadIdx.x;
    const int beg = toff[t], end = toff[t + 1], cnt = end - beg;
    if (cnt <= 0) return;
    const int nstrips = (cnt + 15) >> 4;
    const float* W = (a == 0 ? Wk : (a == 1 ? Wq : Wv)) + (size_t)t * 4096;
    const int m = lane & 15, quad = lane >> 4;

    bf16x8 Bh[2][4], Bl[2][4];
#pragma unroll
    for (int ks = 0; ks < 2; ++ks)
#pragma unroll
        for (int c = 0; c < 4; ++c) load_B_split(W, ks, c, lane, Bh[ks][c], Bl[ks][c]);

    _Float16* out = (a == 0) ? kh16 : (a == 1 ? qout : vout);

    for (int s = blockIdx.x; s < nstrips; s += gridDim.x) {
        int base = beg + s * 16;
        int rA = base + m; if (rA > end - 1) rA = end - 1;
        const float* hp = h + (size_t)nidx[rA] * D;
        bf16x8 A0h, A0l, A1h, A1l;
        load_A_split(hp + quad * 8, A0h, A0l);
        load_A_split(hp + 32 + quad * 8, A1h, A1l);
        f32x4 acc[4];
#pragma unroll
        for (int c = 0; c < 4; ++c) acc[c] = (f32x4){0.f, 0.f, 0.f, 0.f};
        SPLIT_MFMA_BODY(acc, A0h, A0l, A1h, A1l, Bh, Bl)
#pragma unroll
        for (int reg = 0; reg < 4; ++reg) {
            int rr = base + quad * 4 + reg;
            if (rr < end) {
                int nid = nidx[rr];
#pragma unroll
                for (int c = 0; c < 4; ++c)
                    out[(size_t)nid * D + c * 16 + m] = (_Float16)acc[c][reg];
            }
        }
    }
}

// ---------------- fused: per-edge scores (x < SCORE_XB) + V2 build (x >= SCORE_XB) ----------------
// 256-thread blocks, wave-granular strips. score: k fp16 (128B), A split-fp16, q fp16 (128B).
// Edges are (r, dst-block)-sorted; score waves take CONTIGUOUS strip chunks so a wave
// walks whole dst-buckets sequentially (q rows + rec window stay L1/L2-resident).
__global__ void score_v2_kernel(const int* __restrict__ rsrc, const int* __restrict__ rdst,
                                const int* __restrict__ rdpos, const int* __restrict__ offs,
                                const _Float16* __restrict__ kh16,
                                const _Float16* __restrict__ qn, const float* __restrict__ Aatt,
                                const float* __restrict__ pri, int2* __restrict__ rec,
                                const _Float16* __restrict__ vn, const float* __restrict__ Amsg,
                                _Float16* __restrict__ V2, int N, int NBR) {
    const int r = blockIdx.y;
    const int lane = threadIdx.x & 63;
    const int wv = threadIdx.x >> 6;
    const int m = lane & 15, quad = lane >> 4;

    if (blockIdx.x >= SCORE_XB) {
        // ---------------- V2 part ----------------
        const int g = (blockIdx.x - SCORE_XB) * 4 + wv;       // 0..V2_XB*4-1
        const int nstrips = (N + 15) >> 4;
        const float* W = Amsg + (size_t)r * 4096;
        f16x8 B[2][4];
#pragma unroll
        for (int ks = 0; ks < 2; ++ks)
#pragma unroll
            for (int c = 0; c < 4; ++c) B[ks][c] = load_B_frag_f16(W, ks, c, lane);

        for (int s = g; s < nstrips; s += V2_XB * 4) {
            int base = s * 16;
            int rA = base + m; if (rA > N - 1) rA = N - 1;
            f16x8 A0 = *(const f16x8*)(vn + (size_t)rA * D + quad * 8);
            f16x8 A1 = *(const f16x8*)(vn + (size_t)rA * D + 32 + quad * 8);
            f32x4 acc[4];
#pragma unroll
            for (int c = 0; c < 4; ++c) acc[c] = (f32x4){0.f, 0.f, 0.f, 0.f};
#pragma unroll
            for (int c = 0; c < 4; ++c) {
                acc[c] = MFMAH(A0, B[0][c], acc[c]);
                acc[c] = MFMAH(A1, B[1][c], acc[c]);
            }
#pragma unroll
            for (int reg = 0; reg < 4; ++reg) {
                int rr = base + quad * 4 + reg;
                if (rr < N) {
#pragma unroll
                    for (int c = 0; c < 4; ++c)
                        V2[((size_t)rr * RR + r) * D + c * 16 + m] = (_Float16)acc[c][reg];
                }
            }
        }
        return;
    }

    // ---------------- score part ----------------
    const int base0 = offs[N];                 // == E (exclusive prefix of deg)
    const int beg = offs[N + r * NBR] - base0;
    const int end = offs[N + (r + 1) * NBR] - base0;
    const int cnt = end - beg;
    if (cnt <= 0) return;
    const int nstrips = (cnt + 15) >> 4;
    const float scale = pri[r] * 0.125f;
    const float* W = Aatt + (size_t)r * 4096;

    f16x8 Bh[2][4], Bl[2][4];
#pragma unroll
    for (int ks = 0; ks < 2; ++ks)
#pragma unroll
        for (int c = 0; c < 4; ++c) load_B_split_f16(W, ks, c, lane, Bh[ks][c], Bl[ks][c]);

    const int g = blockIdx.x * 4 + wv;                         // 0..SCORE_XB*4-1
    const int nw = SCORE_XB * 4;
    const int chunk = (nstrips + nw - 1) / nw;
    int st0 = g * chunk;
    int st1 = st0 + chunk; if (st1 > nstrips) st1 = nstrips;
    for (int st = st0; st < st1; ++st) {
        int base = st * 16;
        int ia = base + m; if (ia > cnt - 1) ia = cnt - 1;
        int s = rsrc[beg + ia];
        const _Float16* kr = kh16 + (size_t)s * D;   // 128B row
        f16x8 A0 = *(const f16x8*)(kr + quad * 8);
        f16x8 A1 = *(const f16x8*)(kr + 32 + quad * 8);
        f32x4 acc[4];
#pragma unroll
        for (int c = 0; c < 4; ++c) acc[c] = (f32x4){0.f, 0.f, 0.f, 0.f};
#pragma unroll
        for (int c = 0; c < 4; ++c) {
            acc[c] = MFMAH(A0, Bh[0][c], acc[c]);
            acc[c] = MFMAH(A0, Bl[0][c], acc[c]);
            acc[c] = MFMAH(A1, Bh[1][c], acc[c]);
            acc[c] = MFMAH(A1, Bl[1][c], acc[c]);
        }

        float p4[4];
#pragma unroll
        for (int reg = 0; reg < 4; ++reg) {
            int ie = base + quad * 4 + reg; if (ie > cnt - 1) ie = cnt - 1;
            const _Float16* qp = qn + (size_t)rdst[beg + ie] * D + m;
            float pr = acc[0][reg] * (float)qp[0] + acc[1][reg] * (float)qp[16]
                     + acc[2][reg] * (float)qp[32] + acc[3][reg] * (float)qp[48];
#pragma unroll
            for (int d = 8; d; d >>= 1) pr += __shfl_xor(pr, d, 64);
            p4[reg] = pr;
        }
        if (m < 4) {
            int idx = base + quad * 4 + m;
            if (idx < cnt) {
                float v = (m == 0) ? p4[0] : (m == 1) ? p4[1] : (m == 2) ? p4[2] : p4[3];
                int sagain = rsrc[beg + idx];
                int2 rc;
                rc.x = __float_as_int(v * scale);
                rc.y = (sagain << 3) | r;                     // V2 row id
                rec[rdpos[beg + idx]] = rc;
            }
        }
    }
}

// ---------------- fused per-dst softmax+aggregation + output transform ----------------
// grid (AGG_XB, T), 256 threads = 16 quads = 16 same-type nodes per strip.
__global__ void agg_out_kernel(const int* __restrict__ offs, const int2* __restrict__ rec,
                               const _Float16* __restrict__ V2,
                               const float* __restrict__ Wa, const float* __restrict__ skp,
                               const int* __restrict__ toff, const int* __restrict__ nidx,
                               float* __restrict__ out) {
    const int t = blockIdx.y;
    const int beg = toff[t], end = toff[t + 1], cnt = end - beg;
    if (cnt <= 0) return;
    const int nstrips = (cnt + 15) >> 4;
    const int lane = threadIdx.x & 63;
    const int wv = threadIdx.x >> 6;          // 4 waves
    const int quad = lane >> 4, ql = lane & 15;
    const int q16 = wv * 4 + quad;            // node slot 0..15
    const int qb = quad << 4;
    const int m = lane & 15, qd = lane >> 4;  // MFMA roles
    const float sg = 1.f / (1.f + __expf(-skp[t]));

    __shared__ float As[16][68];              // padded stride breaks LDS bank conflicts

    // per-wave B slice (c = wv): 4 fragments, prepped once
    bf16x8 Bh2[2], Bl2[2];
    const float* W = Wa + (size_t)t * 4096;
#pragma unroll
    for (int ks = 0; ks < 2; ++ks) load_B_split(W, ks, wv, lane, Bh2[ks], Bl2[ks]);

    for (int s = blockIdx.x; s < nstrips; s += gridDim.x) {
        int base = beg + s * 16;
        int rr = base + q16; if (rr > end - 1) rr = end - 1;   // tail: duplicate last node
        int i = nidx[rr];
        // ---- aggregation for node i (one quad) ----
        const int ebeg = offs[i], eend = offs[i + 1];
        float mmax = -INFINITY, lsum = 0.f;
        float a0 = 0.f, a1 = 0.f, a2 = 0.f, a3 = 0.f;
        for (int cs = ebeg; cs < eend; cs += 16) {
            int cl = eend - cs; if (cl > 16) cl = 16;
            int2 rc; rc.y = 0;
            float sc = -INFINITY;
            if (ql < cl) { rc = rec[cs + ql]; sc = __int_as_float(rc.x); }
            float cm = sc;
#pragma unroll
            for (int d = 8; d; d >>= 1) cm = fmaxf(cm, __shfl_xor(cm, d, 64));
            float mn = fmaxf(mmax, cm);
            float cf = __expf(mmax - mn);
            float ex = (ql < cl) ? __expf(sc - mn) : 0.f;
            float csum = ex;
#pragma unroll
            for (int d = 8; d; d >>= 1) csum += __shfl_xor(csum, d, 64);
            lsum = lsum * cf + csum;
            a0 *= cf; a1 *= cf; a2 *= cf; a3 *= cf;
            for (int e = 0; e < cl; e += 4) {
                float w0 = __shfl(ex, qb + e, 64),     w1 = __shfl(ex, qb + e + 1, 64);
                float w2 = __shfl(ex, qb + e + 2, 64), w3 = __shfl(ex, qb + e + 3, 64);
                int   i0 = __shfl(rc.y, qb + e, 64),     i1 = __shfl(rc.y, qb + e + 1, 64);
                int   i2 = __shfl(rc.y, qb + e + 2, 64), i3 = __shfl(rc.y, qb + e + 3, 64);
                f16x4 v0 = *(const f16x4*)(V2 + (size_t)i0 * D + ql * 4);
                f16x4 v1 = *(const f16x4*)(V2 + (size_t)i1 * D + ql * 4);
                f16x4 v2 = *(const f16x4*)(V2 + (size_t)i2 * D + ql * 4);
                f16x4 v3 = *(const f16x4*)(V2 + (size_t)i3 * D + ql * 4);
                a0 += w0 * (float)v0[0] + w1 * (float)v1[0] + w2 * (float)v2[0] + w3 * (float)v3[0];
                a1 += w0 * (float)v0[1] + w1 * (float)v1[1] + w2 * (float)v2[1] + w3 * (float)v3[1];
                a2 += w0 * (float)v0[2] + w1 * (float)v1[2] + w2 * (float)v2[2] + w3 * (float)v3[2];
                a3 += w0 * (float)v0[3] + w1 * (float)v1[3] + w2 * (float)v2[3] + w3 * (float)v3[3];
            }
            mmax = mn;
        }
        float inv = 1.f / (lsum + 1e-16f);
        As[q16][ql * 4 + 0] = a0 * inv;
        As[q16][ql * 4 + 1] = a1 * inv;
        As[q16][ql * 4 + 2] = a2 * inv;
        As[q16][ql * 4 + 3] = a3 * inv;
        __syncthreads();

        // ---- out transform: each wave computes its 16-col slice ----
        bf16x8 A0h, A0l, A1h, A1l;
        load_A_split(&As[m][qd * 8], A0h, A0l);
        load_A_split(&As[m][32 + qd * 8], A1h, A1l);
        f32x4 acc = (f32x4){0.f, 0.f, 0.f, 0.f};
        acc = MFMA16(A0h, Bh2[0], acc);
        acc = MFMA16(A0l, Bh2[0], acc);
        acc = MFMA16(A0h, Bl2[0], acc);
        acc = MFMA16(A1h, Bh2[1], acc);
        acc = MFMA16(A1l, Bh2[1], acc);
        acc = MFMA16(A1h, Bl2[1], acc);
#pragma unroll
        for (int reg = 0; reg < 4; ++reg) {
            int rrr = base + qd * 4 + reg;
            if (rrr < end)
                out[(size_t)nidx[rrr] * D + wv * 16 + m] = acc[reg] * sg;
        }
        __syncthreads();   // protect As before next strip
    }
}

// ---------------- launch ----------------
extern "C" void kernel_launch(void* const* d_in, const int* in_sizes, int n_in,
                              void* d_out, int out_size, void* d_ws, size_t ws_size,
                              hipStream_t stream) {
    const float* h     = (const float*)d_in[0];
    const int*   adj   = (const int*)d_in[1];     // [2,E]: src row then dst row
    const int*   etype = (const int*)d_in[2];
    const int*   ntype = (const int*)d_in[3];
    const float* Wk    = (const float*)d_in[6];
    const float* Wq    = (const float*)d_in[7];
    const float* Wv    = (const float*)d_in[8];
    const float* Wa    = (const float*)d_in[9];
    const float* pri   = (const float*)d_in[10];
    const float* Aatt  = (const float*)d_in[11];
    const float* Amsg  = (const float*)d_in[12];
    const float* skp   = (const float*)d_in[13];
    const int N = in_sizes[3];
    const int E = in_sizes[2];
    float* out = (float*)d_out;

    const int NBR = (N + 63) >> DBSHIFT;      // dst-blocks per relation
    const int NB  = RR * NBR;                 // total buckets
    const int Nscan = N + NB;                 // deg | bcnt scanned together

    char* w = (char*)d_ws;
    auto alloc = [&](size_t b) { char* p = w; w += (b + 255) & ~(size_t)255; return p; };
    _Float16* kh16 = (_Float16*)alloc((size_t)N * D * 2);
    _Float16* qn   = (_Float16*)alloc((size_t)N * D * 2);
    _Float16* vn   = (_Float16*)alloc((size_t)N * D * 2);
    _Float16* V2   = (_Float16*)alloc((size_t)N * RR * D * 2);
    // zeroed region: degb[Nscan] | tcnt[8] | bcur[NB] (one memset)
    int* degb = (int*)alloc((size_t)(Nscan + 8 + NB) * 4);
    int* tcnt = degb + Nscan;
    int* bcur = tcnt + 8;
    int* offs = (int*)alloc((size_t)(Nscan + 1) * 4);
    int* erank = (int*)alloc((size_t)E * 4);
    int* toff = (int*)alloc(64);
    int* tcur = (int*)alloc(64);
    int2* rec = (int2*)alloc((size_t)E * 8);
    int* rsrc  = (int*)alloc((size_t)E * 4);
    int* rdst  = (int*)alloc((size_t)E * 4);
    int* rdpos = (int*)alloc((size_t)E * 4);
    int* nidx  = (int*)alloc((size_t)N * 4);
    const int nsb = (Nscan + SCAN_ELEMS - 1) / SCAN_ELEMS;
    int* bsum  = (int*)alloc((size_t)nsb * 4);

    (void)hipMemsetAsync(degb, 0, (size_t)(Nscan + 8 + NB) * 4, stream);

    const int mx = (E > N ? E : N);
    const int histBlocks = (mx + 256 * HIST_CH - 1) / (256 * HIST_CH);
    hist_kernel<<<histBlocks, 256, 0, stream>>>(adj + E, etype, ntype, degb, tcnt, erank, N, E, NBR);
    scan_sum_kernel<<<nsb, SCAN_TPB, 0, stream>>>(degb, bsum, Nscan);
    scan_out_kernel<<<nsb, SCAN_TPB, 0, stream>>>(degb, bsum, nsb, offs, Nscan, 2 * E,
                                                  tcnt, toff, tcur);
    const int scatBlocks = (mx + 256 * SCAT_CH - 1) / (256 * SCAT_CH);
    scatter_kernel<<<scatBlocks, 256, 0, stream>>>(adj, adj + E, etype, ntype,
                                                   offs, erank, tcur, bcur,
                                                   rsrc, rdst, rdpos, nidx, N, E, NBR);
    proj_kernel<<<dim3(128, 3, TT), 64, 0, stream>>>(h, Wk, Wq, Wv, toff, nidx, kh16, qn, vn);
    score_v2_kernel<<<dim3(SCORE_XB + V2_XB, RR), 256, 0, stream>>>(rsrc, rdst, rdpos, offs,
                                                                    kh16, qn, Aatt, pri, rec,
                                                                    vn, Amsg, V2, N, NBR);
    agg_out_kernel<<<dim3(AGG_XB, TT), 256, 0, stream>>>(offs, rec, V2, Wa, skp, toff, nidx, out);
}

// Round 2
// 271.164 us; speedup vs baseline: 1.2100x; 1.2100x over previous
//
#include <hip/hip_runtime.h>
#include <math.h>

typedef float f32x4 __attribute__((ext_vector_type(4)));
typedef short bf16x8 __attribute__((ext_vector_type(8)));
typedef _Float16 f16x8 __attribute__((ext_vector_type(8)));
typedef _Float16 f16x4 __attribute__((ext_vector_type(4)));

#define D 64
#define TT 8
#define RR 8

#define SCAN_TPB 256
#define SCAN_CH 4
#define SCAN_ELEMS (SCAN_TPB * SCAN_CH)   // 1024 elements per block

// HIST_CH/SCAT_CH: edges per thread. 2 (not 8) => 4x blocks => 4x atomic
// latency hiding; hist is memory-side-atomic LATENCY bound (83us at 391
// blocks, VALUBusy 0.4%, occ 15% in round-1 profile).
#define HIST_CH 2
#define SCAT_CH 2
#define SCORE_XB 256                       // score x-blocks (x4 waves = 1024 wave slots, stride 1024)
#define V2_XB 64                           // v2 x-blocks (x4 waves = 256 wave slots, stride 256)
#define AGG_XB 256                         // agg_out x-blocks per type

// ---------------- scalar helpers ----------------
__device__ __forceinline__ float bf2f(unsigned short u) {
    union { unsigned int i; float f; } x;
    x.i = ((unsigned int)u) << 16;
    return x.f;
}
__device__ __forceinline__ unsigned short f2bf(float f) {
    union { float f; unsigned int i; } x;
    x.f = f;
    unsigned int i = x.i;
    unsigned int r = (i + 0x7FFFu + ((i >> 16) & 1u)) >> 16;   // RNE
    return (unsigned short)r;
}
struct BfPair { short hi; short lo; };
__device__ __forceinline__ BfPair split2(float x) {
    BfPair p;
    unsigned short h = f2bf(x);
    p.hi = (short)h;
    p.lo = (short)f2bf(x - bf2f(h));
    return p;
}
__device__ __forceinline__ void load_A_split(const float* __restrict__ p, bf16x8& ah, bf16x8& al) {
#pragma unroll
    for (int i = 0; i < 8; ++i) {
        BfPair s = split2(p[i]);
        ah[i] = s.hi; al[i] = s.lo;
    }
}
// bf16 split B fragment (used by proj/out split GEMMs)
__device__ __forceinline__ void load_B_split(const float* __restrict__ W, int ks, int c, int lane,
                                             bf16x8& bh, bf16x8& bl) {
    int n = lane & 15, q = lane >> 4;
#pragma unroll
    for (int i = 0; i < 8; ++i) {
        BfPair s = split2(W[(ks * 32 + q * 8 + i) * 64 + c * 16 + n]);
        bh[i] = s.hi; bl[i] = s.lo;
    }
}
// fp16 split B fragment (score: A-matrix hi+lo)
__device__ __forceinline__ void load_B_split_f16(const float* __restrict__ W, int ks, int c, int lane,
                                                 f16x8& bh, f16x8& bl) {
    int n = lane & 15, q = lane >> 4;
#pragma unroll
    for (int i = 0; i < 8; ++i) {
        float w = W[(ks * 32 + q * 8 + i) * 64 + c * 16 + n];
        _Float16 h = (_Float16)w;
        bh[i] = h;
        bl[i] = (_Float16)(w - (float)h);
    }
}
// fp16 single B fragment (V2 build)
__device__ __forceinline__ f16x8 load_B_frag_f16(const float* __restrict__ W, int ks, int c, int lane) {
    int n = lane & 15, q = lane >> 4;
    f16x8 r;
#pragma unroll
    for (int i = 0; i < 8; ++i)
        r[i] = (_Float16)W[(ks * 32 + q * 8 + i) * 64 + c * 16 + n];
    return r;
}

#define MFMA16(a, b, c) __builtin_amdgcn_mfma_f32_16x16x32_bf16(a, b, c, 0, 0, 0)
#define MFMAH(a, b, c)  __builtin_amdgcn_mfma_f32_16x16x32_f16(a, b, c, 0, 0, 0)

// 24 bf16 MFMAs: acc += (Ah+Al)@(Bh+Bl) dropping lo*lo
#define SPLIT_MFMA_BODY(acc, A0h, A0l, A1h, A1l, Bh, Bl)          \
    _Pragma("unroll")                                             \
    for (int c = 0; c < 4; ++c) {                                 \
        acc[c] = MFMA16(A0h, Bh[0][c], acc[c]);                   \
        acc[c] = MFMA16(A0l, Bh[0][c], acc[c]);                   \
        acc[c] = MFMA16(A0h, Bl[0][c], acc[c]);                   \
        acc[c] = MFMA16(A1h, Bh[1][c], acc[c]);                   \
        acc[c] = MFMA16(A1l, Bh[1][c], acc[c]);                   \
        acc[c] = MFMA16(A1h, Bl[1][c], acc[c]);                   \
    }

// ---------------- CSR build ----------------
// Grid-strided edges/thread; grid sized for atomic-latency hiding (see HIST_CH).
__global__ void hist_kernel(const int* __restrict__ dst, const int* __restrict__ et,
                            const int* __restrict__ nt,
                            int* __restrict__ deg, int* __restrict__ tcnt, int* __restrict__ rcnt,
                            int* __restrict__ erank, int N, int E) {
    __shared__ int l_r[RR], l_t[TT];
    if (threadIdx.x < RR) l_r[threadIdx.x] = 0;
    if (threadIdx.x < TT) l_t[threadIdx.x] = 0;
    __syncthreads();
    const int stride = gridDim.x * blockDim.x;
    const int tid = blockIdx.x * blockDim.x + threadIdx.x;
#pragma unroll
    for (int i = 0; i < HIST_CH; ++i) {
        int e = tid + i * stride;
        if (e < E) {
            erank[e] = atomicAdd(&deg[dst[e]], 1);
            atomicAdd(&l_r[et[e]], 1);
        }
    }
#pragma unroll
    for (int i = 0; i < HIST_CH; ++i) {
        int n = tid + i * stride;
        if (n < N) atomicAdd(&l_t[nt[n]], 1);
    }
    __syncthreads();
    if (threadIdx.x < RR && l_r[threadIdx.x]) atomicAdd(&rcnt[threadIdx.x], l_r[threadIdx.x]);
    if (threadIdx.x < TT && l_t[threadIdx.x]) atomicAdd(&tcnt[threadIdx.x], l_t[threadIdx.x]);
}

// ---- 2-phase device-wide exclusive scan of deg[0..N) ----
__global__ void scan_sum_kernel(const int* __restrict__ deg, int* __restrict__ bsum, int N) {
    __shared__ int ws[SCAN_TPB / 64];
    int tid = threadIdx.x;
    int base = blockIdx.x * SCAN_ELEMS + tid * SCAN_CH;
    int s = 0;
#pragma unroll
    for (int i = 0; i < SCAN_CH; ++i) {
        int idx = base + i;
        if (idx < N) s += deg[idx];
    }
#pragma unroll
    for (int d = 32; d; d >>= 1) s += __shfl_xor(s, d, 64);
    if ((tid & 63) == 0) ws[tid >> 6] = s;
    __syncthreads();
    if (tid == 0) {
        int t = 0;
#pragma unroll
        for (int i = 0; i < SCAN_TPB / 64; ++i) t += ws[i];
        bsum[blockIdx.x] = t;
    }
}
// scan_out: per-block base via wave prefix of bsum; block 0 writes toff/tcur/roff/rcur.
__global__ void scan_out_kernel(const int* __restrict__ deg, const int* __restrict__ bsum, int nsb,
                                int* __restrict__ off, int N, int Etot,
                                const int* __restrict__ tcnt, int* __restrict__ toff, int* __restrict__ tcur,
                                const int* __restrict__ rcnt, int* __restrict__ roff, int* __restrict__ rcur) {
    __shared__ int ts[SCAN_TPB];
    __shared__ int bb;
    int tid = threadIdx.x;
    if (tid < 64) {
        int v = 0;
        if (nsb <= 64) {
            v = (tid < nsb && tid < blockIdx.x) ? bsum[tid] : 0;
#pragma unroll
            for (int d = 32; d; d >>= 1) v += __shfl_xor(v, d, 64);
        } else if (tid == 0) {
            for (int b = 0; b < blockIdx.x; ++b) v += bsum[b];
        }
        if (tid == 0) bb = v;
    }
    if (blockIdx.x == 0 && tid == 1) {
        int a = 0;
        for (int t = 0; t < TT; ++t) { toff[t] = a; tcur[t] = a; a += tcnt[t]; }
        toff[TT] = a;
        int b2 = 0;
        for (int r = 0; r < RR; ++r) { roff[r] = b2; rcur[r] = b2; b2 += rcnt[r]; }
        roff[RR] = b2;
        off[N] = Etot;
    }
    int base = blockIdx.x * SCAN_ELEMS + tid * SCAN_CH;
    int loc[SCAN_CH];
    int s = 0;
#pragma unroll
    for (int i = 0; i < SCAN_CH; ++i) {
        int idx = base + i;
        int v = (idx < N) ? deg[idx] : 0;
        loc[i] = v; s += v;
    }
    ts[tid] = s;
    __syncthreads();
    for (int sh = 1; sh < SCAN_TPB; sh <<= 1) {
        int v = (tid >= sh) ? ts[tid - sh] : 0;
        __syncthreads();
        ts[tid] += v;
        __syncthreads();
    }
    int run = bb + ((tid > 0) ? ts[tid - 1] : 0);
#pragma unroll
    for (int i = 0; i < SCAN_CH; ++i) {
        int idx = base + i;
        if (idx < N) { off[idx] = run; run += loc[i]; }
    }
}

// scatter: pos = offs[d] + erank[e] (no per-edge global atomics); grid-strided.
__global__ void scatter_kernel(const int* __restrict__ src, const int* __restrict__ dst,
                               const int* __restrict__ et, const int* __restrict__ nt,
                               const int* __restrict__ offs, const int* __restrict__ erank,
                               int* __restrict__ tcur, int* __restrict__ rcur,
                               int* __restrict__ rsrc, int* __restrict__ rdst,
                               int* __restrict__ rdpos, int* __restrict__ nidx, int N, int E) {
    __shared__ int l_r[RR], l_t[TT], base_r[RR], base_t[TT];
    if (threadIdx.x < RR) l_r[threadIdx.x] = 0;
    if (threadIdx.x < TT) l_t[threadIdx.x] = 0;
    __syncthreads();
    const int stride = gridDim.x * blockDim.x;
    const int tid = blockIdx.x * blockDim.x + threadIdx.x;
    int s[SCAT_CH], d[SCAT_CH], r[SCAT_CH], rrank[SCAT_CH];
    int t[SCAT_CH], trank[SCAT_CH];
#pragma unroll
    for (int i = 0; i < SCAT_CH; ++i) {
        int e = tid + i * stride;
        if (e < E) {
            s[i] = src[e]; d[i] = dst[e]; r[i] = et[e];
            rrank[i] = atomicAdd(&l_r[r[i]], 1);
        }
        int n = tid + i * stride;
        if (n < N) {
            t[i] = nt[n];
            trank[i] = atomicAdd(&l_t[t[i]], 1);
        }
    }
    __syncthreads();
    if (threadIdx.x < RR)
        base_r[threadIdx.x] = l_r[threadIdx.x] ? atomicAdd(&rcur[threadIdx.x], l_r[threadIdx.x]) : 0;
    if (threadIdx.x < TT)
        base_t[threadIdx.x] = l_t[threadIdx.x] ? atomicAdd(&tcur[threadIdx.x], l_t[threadIdx.x]) : 0;
    __syncthreads();
#pragma unroll
    for (int i = 0; i < SCAT_CH; ++i) {
        int e = tid + i * stride;
        if (e < E) {
            int pos = offs[d[i]] + erank[e];
            int rp = base_r[r[i]] + rrank[i];
            rsrc[rp] = s[i]; rdst[rp] = d[i]; rdpos[rp] = pos;
        }
        int n = tid + i * stride;
        if (n < N) nidx[base_t[t[i]] + trank[i]] = n;
    }
}

// ---------------- node projections ----------------
// a=0: k -> fp16 row (128B); a=1: q -> fp16 row (128B); a=2: v fp16.
__global__ void proj_kernel(const float* __restrict__ h,
                            const float* __restrict__ Wk, const float* __restrict__ Wq,
                            const float* __restrict__ Wv,
                            const int* __restrict__ toff, const int* __restrict__ nidx,
                            _Float16* __restrict__ kh16,
                            _Float16* __restrict__ qout, _Float16* __restrict__ vout) {
    const int t = blockIdx.z, a = blockIdx.y, lane = threadIdx.x;
    const int beg = toff[t], end = toff[t + 1], cnt = end - beg;
    if (cnt <= 0) return;
    const int nstrips = (cnt + 15) >> 4;
    const float* W = (a == 0 ? Wk : (a == 1 ? Wq : Wv)) + (size_t)t * 4096;
    const int m = lane & 15, quad = lane >> 4;

    bf16x8 Bh[2][4], Bl[2][4];
#pragma unroll
    for (int ks = 0; ks < 2; ++ks)
#pragma unroll
        for (int c = 0; c < 4; ++c) load_B_split(W, ks, c, lane, Bh[ks][c], Bl[ks][c]);

    _Float16* out = (a == 0) ? kh16 : (a == 1 ? qout : vout);

    for (int s = blockIdx.x; s < nstrips; s += gridDim.x) {
        int base = beg + s * 16;
        int rA = base + m; if (rA > end - 1) rA = end - 1;
        const float* hp = h + (size_t)nidx[rA] * D;
        bf16x8 A0h, A0l, A1h, A1l;
        load_A_split(hp + quad * 8, A0h, A0l);
        load_A_split(hp + 32 + quad * 8, A1h, A1l);
        f32x4 acc[4];
#pragma unroll
        for (int c = 0; c < 4; ++c) acc[c] = (f32x4){0.f, 0.f, 0.f, 0.f};
        SPLIT_MFMA_BODY(acc, A0h, A0l, A1h, A1l, Bh, Bl)
#pragma unroll
        for (int reg = 0; reg < 4; ++reg) {
            int rr = base + quad * 4 + reg;
            if (rr < end) {
                int nid = nidx[rr];
#pragma unroll
                for (int c = 0; c < 4; ++c)
                    out[(size_t)nid * D + c * 16 + m] = (_Float16)acc[c][reg];
            }
        }
    }
}

// ---------------- fused: per-edge scores (x < SCORE_XB) + V2 build (x >= SCORE_XB) ----------------
// 256-thread blocks, wave-granular strips. score: k fp16 (128B), A split-fp16, q fp16 (128B).
__global__ void score_v2_kernel(const int* __restrict__ rsrc, const int* __restrict__ rdst,
                                const int* __restrict__ rdpos, const int* __restrict__ roff,
                                const _Float16* __restrict__ kh16,
                                const _Float16* __restrict__ qn, const float* __restrict__ Aatt,
                                const float* __restrict__ pri, int2* __restrict__ rec,
                                const _Float16* __restrict__ vn, const float* __restrict__ Amsg,
                                _Float16* __restrict__ V2, int N) {
    const int r = blockIdx.y;
    const int lane = threadIdx.x & 63;
    const int wv = threadIdx.x >> 6;
    const int m = lane & 15, quad = lane >> 4;

    if (blockIdx.x >= SCORE_XB) {
        // ---------------- V2 part ----------------
        const int g = (blockIdx.x - SCORE_XB) * 4 + wv;       // 0..V2_XB*4-1
        const int nstrips = (N + 15) >> 4;
        const float* W = Amsg + (size_t)r * 4096;
        f16x8 B[2][4];
#pragma unroll
        for (int ks = 0; ks < 2; ++ks)
#pragma unroll
            for (int c = 0; c < 4; ++c) B[ks][c] = load_B_frag_f16(W, ks, c, lane);

        for (int s = g; s < nstrips; s += V2_XB * 4) {
            int base = s * 16;
            int rA = base + m; if (rA > N - 1) rA = N - 1;
            f16x8 A0 = *(const f16x8*)(vn + (size_t)rA * D + quad * 8);
            f16x8 A1 = *(const f16x8*)(vn + (size_t)rA * D + 32 + quad * 8);
            f32x4 acc[4];
#pragma unroll
            for (int c = 0; c < 4; ++c) acc[c] = (f32x4){0.f, 0.f, 0.f, 0.f};
#pragma unroll
            for (int c = 0; c < 4; ++c) {
                acc[c] = MFMAH(A0, B[0][c], acc[c]);
                acc[c] = MFMAH(A1, B[1][c], acc[c]);
            }
#pragma unroll
            for (int reg = 0; reg < 4; ++reg) {
                int rr = base + quad * 4 + reg;
                if (rr < N) {
#pragma unroll
                    for (int c = 0; c < 4; ++c)
                        V2[((size_t)rr * RR + r) * D + c * 16 + m] = (_Float16)acc[c][reg];
                }
            }
        }
        return;
    }

    // ---------------- score part ----------------
    const int beg = roff[r], end = roff[r + 1], cnt = end - beg;
    if (cnt <= 0) return;
    const int nstrips = (cnt + 15) >> 4;
    const float scale = pri[r] * 0.125f;
    const float* W = Aatt + (size_t)r * 4096;

    f16x8 Bh[2][4], Bl[2][4];
#pragma unroll
    for (int ks = 0; ks < 2; ++ks)
#pragma unroll
        for (int c = 0; c < 4; ++c) load_B_split_f16(W, ks, c, lane, Bh[ks][c], Bl[ks][c]);

    const int g = blockIdx.x * 4 + wv;                         // 0..SCORE_XB*4-1
    for (int st = g; st < nstrips; st += SCORE_XB * 4) {
        int base = st * 16;
        int ia = base + m; if (ia > cnt - 1) ia = cnt - 1;
        int s = rsrc[beg + ia];
        const _Float16* kr = kh16 + (size_t)s * D;   // 128B row
        f16x8 A0 = *(const f16x8*)(kr + quad * 8);
        f16x8 A1 = *(const f16x8*)(kr + 32 + quad * 8);
        f32x4 acc[4];
#pragma unroll
        for (int c = 0; c < 4; ++c) acc[c] = (f32x4){0.f, 0.f, 0.f, 0.f};
#pragma unroll
        for (int c = 0; c < 4; ++c) {
            acc[c] = MFMAH(A0, Bh[0][c], acc[c]);
            acc[c] = MFMAH(A0, Bl[0][c], acc[c]);
            acc[c] = MFMAH(A1, Bh[1][c], acc[c]);
            acc[c] = MFMAH(A1, Bl[1][c], acc[c]);
        }

        float p4[4];
#pragma unroll
        for (int reg = 0; reg < 4; ++reg) {
            int ie = base + quad * 4 + reg; if (ie > cnt - 1) ie = cnt - 1;
            const _Float16* qp = qn + (size_t)rdst[beg + ie] * D + m;
            float pr = acc[0][reg] * (float)qp[0] + acc[1][reg] * (float)qp[16]
                     + acc[2][reg] * (float)qp[32] + acc[3][reg] * (float)qp[48];
#pragma unroll
            for (int d = 8; d; d >>= 1) pr += __shfl_xor(pr, d, 64);
            p4[reg] = pr;
        }
        if (m < 4) {
            int idx = base + quad * 4 + m;
            if (idx < cnt) {
                float v = (m == 0) ? p4[0] : (m == 1) ? p4[1] : (m == 2) ? p4[2] : p4[3];
                int sagain = rsrc[beg + idx];
                int2 rc;
                rc.x = __float_as_int(v * scale);
                rc.y = (sagain << 3) | r;                     // V2 row id
                rec[rdpos[beg + idx]] = rc;
            }
        }
    }
}

// ---------------- fused per-dst softmax+aggregation + output transform ----------------
// grid (AGG_XB, T), 256 threads = 16 quads = 16 same-type nodes per strip.
__global__ void agg_out_kernel(const int* __restrict__ offs, const int2* __restrict__ rec,
                               const _Float16* __restrict__ V2,
                               const float* __restrict__ Wa, const float* __restrict__ skp,
                               const int* __restrict__ toff, const int* __restrict__ nidx,
                               float* __restrict__ out) {
    const int t = blockIdx.y;
    const int beg = toff[t], end = toff[t + 1], cnt = end - beg;
    if (cnt <= 0) return;
    const int nstrips = (cnt + 15) >> 4;
    const int lane = threadIdx.x & 63;
    const int wv = threadIdx.x >> 6;          // 4 waves
    const int quad = lane >> 4, ql = lane & 15;
    const int q16 = wv * 4 + quad;            // node slot 0..15
    const int qb = quad << 4;
    const int m = lane & 15, qd = lane >> 4;  // MFMA roles
    const float sg = 1.f / (1.f + __expf(-skp[t]));

    __shared__ float As[16][68];              // padded stride breaks LDS bank conflicts

    // per-wave B slice (c = wv): 4 fragments, prepped once
    bf16x8 Bh2[2], Bl2[2];
    const float* W = Wa + (size_t)t * 4096;
#pragma unroll
    for (int ks = 0; ks < 2; ++ks) load_B_split(W, ks, wv, lane, Bh2[ks], Bl2[ks]);

    for (int s = blockIdx.x; s < nstrips; s += gridDim.x) {
        int base = beg + s * 16;
        int rr = base + q16; if (rr > end - 1) rr = end - 1;   // tail: duplicate last node
        int i = nidx[rr];
        // ---- aggregation for node i (one quad) ----
        const int ebeg = offs[i], eend = offs[i + 1];
        float mmax = -INFINITY, lsum = 0.f;
        float a0 = 0.f, a1 = 0.f, a2 = 0.f, a3 = 0.f;
        for (int cs = ebeg; cs < eend; cs += 16) {
            int cl = eend - cs; if (cl > 16) cl = 16;
            int2 rc; rc.y = 0;
            float sc = -INFINITY;
            if (ql < cl) { rc = rec[cs + ql]; sc = __int_as_float(rc.x); }
            float cm = sc;
#pragma unroll
            for (int d = 8; d; d >>= 1) cm = fmaxf(cm, __shfl_xor(cm, d, 64));
            float mn = fmaxf(mmax, cm);
            float cf = __expf(mmax - mn);
            float ex = (ql < cl) ? __expf(sc - mn) : 0.f;
            float csum = ex;
#pragma unroll
            for (int d = 8; d; d >>= 1) csum += __shfl_xor(csum, d, 64);
            lsum = lsum * cf + csum;
            a0 *= cf; a1 *= cf; a2 *= cf; a3 *= cf;
            for (int e = 0; e < cl; e += 4) {
                float w0 = __shfl(ex, qb + e, 64),     w1 = __shfl(ex, qb + e + 1, 64);
                float w2 = __shfl(ex, qb + e + 2, 64), w3 = __shfl(ex, qb + e + 3, 64);
                int   i0 = __shfl(rc.y, qb + e, 64),     i1 = __shfl(rc.y, qb + e + 1, 64);
                int   i2 = __shfl(rc.y, qb + e + 2, 64), i3 = __shfl(rc.y, qb + e + 3, 64);
                f16x4 v0 = *(const f16x4*)(V2 + (size_t)i0 * D + ql * 4);
                f16x4 v1 = *(const f16x4*)(V2 + (size_t)i1 * D + ql * 4);
                f16x4 v2 = *(const f16x4*)(V2 + (size_t)i2 * D + ql * 4);
                f16x4 v3 = *(const f16x4*)(V2 + (size_t)i3 * D + ql * 4);
                a0 += w0 * (float)v0[0] + w1 * (float)v1[0] + w2 * (float)v2[0] + w3 * (float)v3[0];
                a1 += w0 * (float)v0[1] + w1 * (float)v1[1] + w2 * (float)v2[1] + w3 * (float)v3[1];
                a2 += w0 * (float)v0[2] + w1 * (float)v1[2] + w2 * (float)v2[2] + w3 * (float)v3[2];
                a3 += w0 * (float)v0[3] + w1 * (float)v1[3] + w2 * (float)v2[3] + w3 * (float)v3[3];
            }
            mmax = mn;
        }
        float inv = 1.f / (lsum + 1e-16f);
        As[q16][ql * 4 + 0] = a0 * inv;
        As[q16][ql * 4 + 1] = a1 * inv;
        As[q16][ql * 4 + 2] = a2 * inv;
        As[q16][ql * 4 + 3] = a3 * inv;
        __syncthreads();

        // ---- out transform: each wave computes its 16-col slice (identical MFMA seq) ----
        bf16x8 A0h, A0l, A1h, A1l;
        load_A_split(&As[m][qd * 8], A0h, A0l);
        load_A_split(&As[m][32 + qd * 8], A1h, A1l);
        f32x4 acc = (f32x4){0.f, 0.f, 0.f, 0.f};
        acc = MFMA16(A0h, Bh2[0], acc);
        acc = MFMA16(A0l, Bh2[0], acc);
        acc = MFMA16(A0h, Bl2[0], acc);
        acc = MFMA16(A1h, Bh2[1], acc);
        acc = MFMA16(A1l, Bh2[1], acc);
        acc = MFMA16(A1h, Bl2[1], acc);
#pragma unroll
        for (int reg = 0; reg < 4; ++reg) {
            int rrr = base + qd * 4 + reg;
            if (rrr < end)
                out[(size_t)nidx[rrr] * D + wv * 16 + m] = acc[reg] * sg;
        }
        __syncthreads();   // protect As before next strip
    }
}

// ---------------- launch ----------------
extern "C" void kernel_launch(void* const* d_in, const int* in_sizes, int n_in,
                              void* d_out, int out_size, void* d_ws, size_t ws_size,
                              hipStream_t stream) {
    const float* h     = (const float*)d_in[0];
    const int*   adj   = (const int*)d_in[1];     // [2,E]: src row then dst row
    const int*   etype = (const int*)d_in[2];
    const int*   ntype = (const int*)d_in[3];
    const float* Wk    = (const float*)d_in[6];
    const float* Wq    = (const float*)d_in[7];
    const float* Wv    = (const float*)d_in[8];
    const float* Wa    = (const float*)d_in[9];
    const float* pri   = (const float*)d_in[10];
    const float* Aatt  = (const float*)d_in[11];
    const float* Amsg  = (const float*)d_in[12];
    const float* skp   = (const float*)d_in[13];
    const int N = in_sizes[3];
    const int E = in_sizes[2];
    float* out = (float*)d_out;

    char* w = (char*)d_ws;
    auto alloc = [&](size_t b) { char* p = w; w += (b + 255) & ~(size_t)255; return p; };
    _Float16* kh16 = (_Float16*)alloc((size_t)N * D * 2);
    _Float16* qn   = (_Float16*)alloc((size_t)N * D * 2);
    _Float16* vn   = (_Float16*)alloc((size_t)N * D * 2);
    _Float16* V2   = (_Float16*)alloc((size_t)N * RR * D * 2);
    int* deg  = (int*)alloc((size_t)(N + 16) * 4);
    int* tcnt = deg + N;
    int* rcnt = deg + N + 8;
    int* offs = (int*)alloc((size_t)(N + 1) * 4);
    int* erank = (int*)alloc((size_t)E * 4);
    int* toff = (int*)alloc(64);
    int* tcur = (int*)alloc(64);
    int* roff = (int*)alloc(64);
    int* rcur = (int*)alloc(64);
    int2* rec = (int2*)alloc((size_t)E * 8);
    int* rsrc  = (int*)alloc((size_t)E * 4);
    int* rdst  = (int*)alloc((size_t)E * 4);
    int* rdpos = (int*)alloc((size_t)E * 4);
    int* nidx  = (int*)alloc((size_t)N * 4);
    const int nsb = (N + SCAN_ELEMS - 1) / SCAN_ELEMS;
    int* bsum  = (int*)alloc((size_t)nsb * 4);

    (void)hipMemsetAsync(deg, 0, (size_t)(N + 16) * 4, stream);

    const int mx = (E > N ? E : N);
    const int histBlocks = (mx + 256 * HIST_CH - 1) / (256 * HIST_CH);
    hist_kernel<<<histBlocks, 256, 0, stream>>>(adj + E, etype, ntype, deg, tcnt, rcnt, erank, N, E);
    scan_sum_kernel<<<nsb, SCAN_TPB, 0, stream>>>(deg, bsum, N);
    scan_out_kernel<<<nsb, SCAN_TPB, 0, stream>>>(deg, bsum, nsb, offs, N, E,
                                                  tcnt, toff, tcur, rcnt, roff, rcur);
    const int scatBlocks = (mx + 256 * SCAT_CH - 1) / (256 * SCAT_CH);
    scatter_kernel<<<scatBlocks, 256, 0, stream>>>(adj, adj + E, etype, ntype,
                                                   offs, erank, tcur, rcur,
                                                   rsrc, rdst, rdpos, nidx, N, E);
    proj_kernel<<<dim3(128, 3, TT), 64, 0, stream>>>(h, Wk, Wq, Wv, toff, nidx, kh16, qn, vn);
    score_v2_kernel<<<dim3(SCORE_XB + V2_XB, RR), 256, 0, stream>>>(rsrc, rdst, rdpos, roff,
                                                                    kh16, qn, Aatt, pri, rec,
                                                                    vn, Amsg, V2, N);
    agg_out_kernel<<<dim3(AGG_XB, TT), 256, 0, stream>>>(offs, rec, V2, Wa, skp, toff, nidx, out);
}

// Round 4
// 256.223 us; speedup vs baseline: 1.2805x; 1.0583x over previous
//
#include <hip/hip_runtime.h>
#include <math.h>

typedef float f32x4 __attribute__((ext_vector_type(4)));
typedef short bf16x8 __attribute__((ext_vector_type(8)));
typedef _Float16 f16x8 __attribute__((ext_vector_type(8)));
typedef _Float16 f16x4 __attribute__((ext_vector_type(4)));

#define D 64
#define TT 8
#define RR 8

#define SCAN_TPB 256
#define SCAN_CH 4
#define SCAN_ELEMS (SCAN_TPB * SCAN_CH)   // 1024 elements per block

// r0 values (257.9us). r2 tried CH=2 (4x blocks): net -13us regression, reverted.
#define HIST_CH 8
#define SCAT_CH 4
#define SCORE_XB 256                       // score x-blocks (x4 waves = 1024 wave slots, stride 1024)
#define V2_XB 64                           // v2 x-blocks (x4 waves = 256 wave slots, stride 256)
#define AGG_XB 256                         // agg_out x-blocks per type

// ---------------- scalar helpers ----------------
__device__ __forceinline__ float bf2f(unsigned short u) {
    union { unsigned int i; float f; } x;
    x.i = ((unsigned int)u) << 16;
    return x.f;
}
__device__ __forceinline__ unsigned short f2bf(float f) {
    union { float f; unsigned int i; } x;
    x.f = f;
    unsigned int i = x.i;
    unsigned int r = (i + 0x7FFFu + ((i >> 16) & 1u)) >> 16;   // RNE
    return (unsigned short)r;
}
struct BfPair { short hi; short lo; };
__device__ __forceinline__ BfPair split2(float x) {
    BfPair p;
    unsigned short h = f2bf(x);
    p.hi = (short)h;
    p.lo = (short)f2bf(x - bf2f(h));
    return p;
}
__device__ __forceinline__ void load_A_split(const float* __restrict__ p, bf16x8& ah, bf16x8& al) {
#pragma unroll
    for (int i = 0; i < 8; ++i) {
        BfPair s = split2(p[i]);
        ah[i] = s.hi; al[i] = s.lo;
    }
}
// bf16 split B fragment, canonical cols (agg_out: col = c*16+n)
__device__ __forceinline__ void load_B_split(const float* __restrict__ W, int ks, int c, int lane,
                                             bf16x8& bh, bf16x8& bl) {
    int n = lane & 15, q = lane >> 4;
#pragma unroll
    for (int i = 0; i < 8; ++i) {
        BfPair s = split2(W[(ks * 32 + q * 8 + i) * 64 + c * 16 + n]);
        bh[i] = s.hi; bl[i] = s.lo;
    }
}
// bf16 split B fragment, PERMUTED cols (proj: col = n*4+c -> lane n holds out cols 4n..4n+3,
// enabling one f16x4 store per reg instead of 4 scalar stores; store address carries the
// permutation so the MEMORY layout of kh16/qn/vn stays natural feature order)
__device__ __forceinline__ void load_B_splitp(const float* __restrict__ W, int ks, int c, int lane,
                                              bf16x8& bh, bf16x8& bl) {
    int n = lane & 15, q = lane >> 4;
#pragma unroll
    for (int i = 0; i < 8; ++i) {
        BfPair s = split2(W[(ks * 32 + q * 8 + i) * 64 + n * 4 + c]);
        bh[i] = s.hi; bl[i] = s.lo;
    }
}
// fp16 split B fragment, PERMUTED cols (score: lane n's acc holds cols 4n..4n+3 ->
// q-dot loads one f16x4 per reg; column permutation is legal since the dot reduces all 64 cols)
__device__ __forceinline__ void load_B_split_f16(const float* __restrict__ W, int ks, int c, int lane,
                                                 f16x8& bh, f16x8& bl) {
    int n = lane & 15, q = lane >> 4;
#pragma unroll
    for (int i = 0; i < 8; ++i) {
        float w = W[(ks * 32 + q * 8 + i) * 64 + n * 4 + c];
        _Float16 h = (_Float16)w;
        bh[i] = h;
        bl[i] = (_Float16)(w - (float)h);
    }
}
// fp16 single B fragment, PERMUTED cols (V2 build: vector f16x4 stores)
__device__ __forceinline__ f16x8 load_B_frag_f16(const float* __restrict__ W, int ks, int c, int lane) {
    int n = lane & 15, q = lane >> 4;
    f16x8 r;
#pragma unroll
    for (int i = 0; i < 8; ++i)
        r[i] = (_Float16)W[(ks * 32 + q * 8 + i) * 64 + n * 4 + c];
    return r;
}

#define MFMA16(a, b, c) __builtin_amdgcn_mfma_f32_16x16x32_bf16(a, b, c, 0, 0, 0)
#define MFMAH(a, b, c)  __builtin_amdgcn_mfma_f32_16x16x32_f16(a, b, c, 0, 0, 0)

// 24 bf16 MFMAs: acc += (Ah+Al)@(Bh+Bl) dropping lo*lo
#define SPLIT_MFMA_BODY(acc, A0h, A0l, A1h, A1l, Bh, Bl)          \
    _Pragma("unroll")                                             \
    for (int c = 0; c < 4; ++c) {                                 \
        acc[c] = MFMA16(A0h, Bh[0][c], acc[c]);                   \
        acc[c] = MFMA16(A0l, Bh[0][c], acc[c]);                   \
        acc[c] = MFMA16(A0h, Bl[0][c], acc[c]);                   \
        acc[c] = MFMA16(A1h, Bh[1][c], acc[c]);                   \
        acc[c] = MFMA16(A1l, Bh[1][c], acc[c]);                   \
        acc[c] = MFMA16(A1h, Bl[1][c], acc[c]);                   \
    }

// ---------------- CSR build ----------------
__global__ void hist_kernel(const int* __restrict__ dst, const int* __restrict__ et,
                            const int* __restrict__ nt,
                            int* __restrict__ deg, int* __restrict__ tcnt, int* __restrict__ rcnt,
                            int* __restrict__ erank, int N, int E) {
    __shared__ int l_r[RR], l_t[TT];
    if (threadIdx.x < RR) l_r[threadIdx.x] = 0;
    if (threadIdx.x < TT) l_t[threadIdx.x] = 0;
    __syncthreads();
    const int stride = gridDim.x * blockDim.x;
    const int tid = blockIdx.x * blockDim.x + threadIdx.x;
#pragma unroll
    for (int i = 0; i < HIST_CH; ++i) {
        int e = tid + i * stride;
        if (e < E) {
            erank[e] = atomicAdd(&deg[dst[e]], 1);
            atomicAdd(&l_r[et[e]], 1);
        }
    }
#pragma unroll
    for (int i = 0; i < HIST_CH; ++i) {
        int n = tid + i * stride;
        if (n < N) atomicAdd(&l_t[nt[n]], 1);
    }
    __syncthreads();
    if (threadIdx.x < RR && l_r[threadIdx.x]) atomicAdd(&rcnt[threadIdx.x], l_r[threadIdx.x]);
    if (threadIdx.x < TT && l_t[threadIdx.x]) atomicAdd(&tcnt[threadIdx.x], l_t[threadIdx.x]);
}

// ---- 2-phase device-wide exclusive scan of deg[0..N) ----
__global__ void scan_sum_kernel(const int* __restrict__ deg, int* __restrict__ bsum, int N) {
    __shared__ int ws[SCAN_TPB / 64];
    int tid = threadIdx.x;
    int base = blockIdx.x * SCAN_ELEMS + tid * SCAN_CH;
    int s = 0;
#pragma unroll
    for (int i = 0; i < SCAN_CH; ++i) {
        int idx = base + i;
        if (idx < N) s += deg[idx];
    }
#pragma unroll
    for (int d = 32; d; d >>= 1) s += __shfl_xor(s, d, 64);
    if ((tid & 63) == 0) ws[tid >> 6] = s;
    __syncthreads();
    if (tid == 0) {
        int t = 0;
#pragma unroll
        for (int i = 0; i < SCAN_TPB / 64; ++i) t += ws[i];
        bsum[blockIdx.x] = t;
    }
}
__global__ void scan_out_kernel(const int* __restrict__ deg, const int* __restrict__ bsum, int nsb,
                                int* __restrict__ off, int N, int Etot,
                                const int* __restrict__ tcnt, int* __restrict__ toff, int* __restrict__ tcur,
                                const int* __restrict__ rcnt, int* __restrict__ roff, int* __restrict__ rcur) {
    __shared__ int ts[SCAN_TPB];
    __shared__ int bb;
    int tid = threadIdx.x;
    if (tid < 64) {
        int v = 0;
        if (nsb <= 64) {
            v = (tid < nsb && tid < blockIdx.x) ? bsum[tid] : 0;
#pragma unroll
            for (int d = 32; d; d >>= 1) v += __shfl_xor(v, d, 64);
        } else if (tid == 0) {
            for (int b = 0; b < blockIdx.x; ++b) v += bsum[b];
        }
        if (tid == 0) bb = v;
    }
    if (blockIdx.x == 0 && tid == 1) {
        int a = 0;
        for (int t = 0; t < TT; ++t) { toff[t] = a; tcur[t] = a; a += tcnt[t]; }
        toff[TT] = a;
        int b2 = 0;
        for (int r = 0; r < RR; ++r) { roff[r] = b2; rcur[r] = b2; b2 += rcnt[r]; }
        roff[RR] = b2;
        off[N] = Etot;
    }
    int base = blockIdx.x * SCAN_ELEMS + tid * SCAN_CH;
    int loc[SCAN_CH];
    int s = 0;
#pragma unroll
    for (int i = 0; i < SCAN_CH; ++i) {
        int idx = base + i;
        int v = (idx < N) ? deg[idx] : 0;
        loc[i] = v; s += v;
    }
    ts[tid] = s;
    __syncthreads();
    for (int sh = 1; sh < SCAN_TPB; sh <<= 1) {
        int v = (tid >= sh) ? ts[tid - sh] : 0;
        __syncthreads();
        ts[tid] += v;
        __syncthreads();
    }
    int run = bb + ((tid > 0) ? ts[tid - 1] : 0);
#pragma unroll
    for (int i = 0; i < SCAN_CH; ++i) {
        int idx = base + i;
        if (idx < N) { off[idx] = run; run += loc[i]; }
    }
}

// scatter: pos = offs[d] + erank[e] (no per-edge global atomics); grid-strided.
__global__ void scatter_kernel(const int* __restrict__ src, const int* __restrict__ dst,
                               const int* __restrict__ et, const int* __restrict__ nt,
                               const int* __restrict__ offs, const int* __restrict__ erank,
                               int* __restrict__ tcur, int* __restrict__ rcur,
                               int* __restrict__ rsrc, int* __restrict__ rdst,
                               int* __restrict__ rdpos, int* __restrict__ nidx, int N, int E) {
    __shared__ int l_r[RR], l_t[TT], base_r[RR], base_t[TT];
    if (threadIdx.x < RR) l_r[threadIdx.x] = 0;
    if (threadIdx.x < TT) l_t[threadIdx.x] = 0;
    __syncthreads();
    const int stride = gridDim.x * blockDim.x;
    const int tid = blockIdx.x * blockDim.x + threadIdx.x;
    int s[SCAT_CH], d[SCAT_CH], r[SCAT_CH], rrank[SCAT_CH];
    int t[SCAT_CH], trank[SCAT_CH];
#pragma unroll
    for (int i = 0; i < SCAT_CH; ++i) {
        int e = tid + i * stride;
        if (e < E) {
            s[i] = src[e]; d[i] = dst[e]; r[i] = et[e];
            rrank[i] = atomicAdd(&l_r[r[i]], 1);
        }
        int n = tid + i * stride;
        if (n < N) {
            t[i] = nt[n];
            trank[i] = atomicAdd(&l_t[t[i]], 1);
        }
    }
    __syncthreads();
    if (threadIdx.x < RR)
        base_r[threadIdx.x] = l_r[threadIdx.x] ? atomicAdd(&rcur[threadIdx.x], l_r[threadIdx.x]) : 0;
    if (threadIdx.x < TT)
        base_t[threadIdx.x] = l_t[threadIdx.x] ? atomicAdd(&tcur[threadIdx.x], l_t[threadIdx.x]) : 0;
    __syncthreads();
#pragma unroll
    for (int i = 0; i < SCAT_CH; ++i) {
        int e = tid + i * stride;
        if (e < E) {
            int pos = offs[d[i]] + erank[e];
            int rp = base_r[r[i]] + rrank[i];
            rsrc[rp] = s[i]; rdst[rp] = d[i]; rdpos[rp] = pos;
        }
        int n = tid + i * stride;
        if (n < N) nidx[base_t[t[i]] + trank[i]] = n;
    }
}

// ---------------- node projections ----------------
// a=0: k -> fp16 row (128B); a=1: q -> fp16 row; a=2: v fp16.
// Permuted B cols: lane m's acc holds cols 4m..4m+3 -> one f16x4 store per reg.
__global__ void proj_kernel(const float* __restrict__ h,
                            const float* __restrict__ Wk, const float* __restrict__ Wq,
                            const float* __restrict__ Wv,
                            const int* __restrict__ toff, const int* __restrict__ nidx,
                            _Float16* __restrict__ kh16,
                            _Float16* __restrict__ qout, _Float16* __restrict__ vout) {
    const int t = blockIdx.z, a = blockIdx.y, lane = threadIdx.x;
    const int beg = toff[t], end = toff[t + 1], cnt = end - beg;
    if (cnt <= 0) return;
    const int nstrips = (cnt + 15) >> 4;
    const float* W = (a == 0 ? Wk : (a == 1 ? Wq : Wv)) + (size_t)t * 4096;
    const int m = lane & 15, quad = lane >> 4;

    bf16x8 Bh[2][4], Bl[2][4];
#pragma unroll
    for (int ks = 0; ks < 2; ++ks)
#pragma unroll
        for (int c = 0; c < 4; ++c) load_B_splitp(W, ks, c, lane, Bh[ks][c], Bl[ks][c]);

    _Float16* out = (a == 0) ? kh16 : (a == 1 ? qout : vout);

    for (int s = blockIdx.x; s < nstrips; s += gridDim.x) {
        int base = beg + s * 16;
        int rA = base + m; if (rA > end - 1) rA = end - 1;
        const float* hp = h + (size_t)nidx[rA] * D;
        bf16x8 A0h, A0l, A1h, A1l;
        load_A_split(hp + quad * 8, A0h, A0l);
        load_A_split(hp + 32 + quad * 8, A1h, A1l);
        f32x4 acc[4];
#pragma unroll
        for (int c = 0; c < 4; ++c) acc[c] = (f32x4){0.f, 0.f, 0.f, 0.f};
        SPLIT_MFMA_BODY(acc, A0h, A0l, A1h, A1l, Bh, Bl)
#pragma unroll
        for (int reg = 0; reg < 4; ++reg) {
            int rr = base + quad * 4 + reg;
            if (rr < end) {
                int nid = nidx[rr];
                f16x4 o;
#pragma unroll
                for (int c = 0; c < 4; ++c) o[c] = (_Float16)acc[c][reg];
                *(f16x4*)(out + (size_t)nid * D + m * 4) = o;
            }
        }
    }
}

// ---------------- fused: per-edge scores (x < SCORE_XB) + V2 build (x >= SCORE_XB) ----------------
// score: 2-deep software pipeline (meta s/d/p prefetched 2 strips ahead, k-rows 1 ahead),
// permuted-B q-dot (one f16x4 load per reg), shuffle-distributed rdst/rdpos/rsrc.
__global__ void score_v2_kernel(const int* __restrict__ rsrc, const int* __restrict__ rdst,
                                const int* __restrict__ rdpos, const int* __restrict__ roff,
                                const _Float16* __restrict__ kh16,
                                const _Float16* __restrict__ qn, const float* __restrict__ Aatt,
                                const float* __restrict__ pri, int2* __restrict__ rec,
                                const _Float16* __restrict__ vn, const float* __restrict__ Amsg,
                                _Float16* __restrict__ V2, int N) {
    const int r = blockIdx.y;
    const int lane = threadIdx.x & 63;
    const int wv = threadIdx.x >> 6;
    const int m = lane & 15, quad = lane >> 4;

    if (blockIdx.x >= SCORE_XB) {
        // ---------------- V2 part ----------------
        const int g = (blockIdx.x - SCORE_XB) * 4 + wv;       // 0..V2_XB*4-1
        const int nstrips = (N + 15) >> 4;
        const float* W = Amsg + (size_t)r * 4096;
        f16x8 B[2][4];
#pragma unroll
        for (int ks = 0; ks < 2; ++ks)
#pragma unroll
            for (int c = 0; c < 4; ++c) B[ks][c] = load_B_frag_f16(W, ks, c, lane);

        for (int s = g; s < nstrips; s += V2_XB * 4) {
            int base = s * 16;
            int rA = base + m; if (rA > N - 1) rA = N - 1;
            f16x8 A0 = *(const f16x8*)(vn + (size_t)rA * D + quad * 8);
            f16x8 A1 = *(const f16x8*)(vn + (size_t)rA * D + 32 + quad * 8);
            f32x4 acc[4];
#pragma unroll
            for (int c = 0; c < 4; ++c) acc[c] = (f32x4){0.f, 0.f, 0.f, 0.f};
#pragma unroll
            for (int c = 0; c < 4; ++c) {
                acc[c] = MFMAH(A0, B[0][c], acc[c]);
                acc[c] = MFMAH(A1, B[1][c], acc[c]);
            }
#pragma unroll
            for (int reg = 0; reg < 4; ++reg) {
                int rr = base + quad * 4 + reg;
                if (rr < N) {
                    f16x4 o;
#pragma unroll
                    for (int c = 0; c < 4; ++c) o[c] = (_Float16)acc[c][reg];
                    *(f16x4*)(V2 + ((size_t)rr * RR + r) * D + m * 4) = o;
                }
            }
        }
        return;
    }

    // ---------------- score part ----------------
    const int beg = roff[r], end = roff[r + 1], cnt = end - beg;
    if (cnt <= 0) return;
    const int nstrips = (cnt + 15) >> 4;
    const float scale = pri[r] * 0.125f;
    const float* W = Aatt + (size_t)r * 4096;

    f16x8 Bh[2][4], Bl[2][4];
#pragma unroll
    for (int ks = 0; ks < 2; ++ks)
#pragma unroll
        for (int c = 0; c < 4; ++c) load_B_split_f16(W, ks, c, lane, Bh[ks][c], Bl[ks][c]);

    const int NW = SCORE_XB * 4;
    const int g = blockIdx.x * 4 + wv;                         // 0..NW-1
    if (g >= nstrips) return;

    // pipeline state: current strip's meta+k in regs, next strip's meta in regs
    int sC, dC, pC, sN = 0, dN = 0, pN = 0;
    f16x8 A0, A1;
    {
        int ia = g * 16 + m; if (ia > cnt - 1) ia = cnt - 1;
        sC = rsrc[beg + ia]; dC = rdst[beg + ia]; pC = rdpos[beg + ia];
    }
    {
        const _Float16* kr = kh16 + (size_t)sC * D;
        A0 = *(const f16x8*)(kr + quad * 8);
        A1 = *(const f16x8*)(kr + 32 + quad * 8);
    }
    if (g + NW < nstrips) {
        int ia = (g + NW) * 16 + m; if (ia > cnt - 1) ia = cnt - 1;
        sN = rsrc[beg + ia]; dN = rdst[beg + ia]; pN = rdpos[beg + ia];
    }

    for (int st = g; st < nstrips; st += NW) {
        const int base = st * 16;
        f32x4 acc[4];
#pragma unroll
        for (int c = 0; c < 4; ++c) acc[c] = (f32x4){0.f, 0.f, 0.f, 0.f};
#pragma unroll
        for (int c = 0; c < 4; ++c) {
            acc[c] = MFMAH(A0, Bh[0][c], acc[c]);
            acc[c] = MFMAH(A0, Bl[0][c], acc[c]);
            acc[c] = MFMAH(A1, Bh[1][c], acc[c]);
            acc[c] = MFMAH(A1, Bl[1][c], acc[c]);
        }

        // issue next strip's k-rows (sN arrived >=1 iter ago); latency hides under q-dot
        const bool hN = (st + NW) < nstrips;
        f16x8 A0n, A1n;
        if (hN) {
            const _Float16* kr = kh16 + (size_t)sN * D;
            A0n = *(const f16x8*)(kr + quad * 8);
            A1n = *(const f16x8*)(kr + 32 + quad * 8);
        }
        // issue meta for strip st+2*NW
        int sNN = 0, dNN = 0, pNN = 0;
        const bool hNN = (st + 2 * NW) < nstrips;
        if (hNN) {
            int ia = (st + 2 * NW) * 16 + m; if (ia > cnt - 1) ia = cnt - 1;
            sNN = rsrc[beg + ia]; dNN = rdst[beg + ia]; pNN = rdpos[beg + ia];
        }

        // q-dot: permuted B -> lane m holds cols 4m..4m+3; one f16x4 load per reg
        float p4[4];
#pragma unroll
        for (int reg = 0; reg < 4; ++reg) {
            int dd = __shfl(dC, quad * 4 + reg, 64);
            f16x4 q4 = *(const f16x4*)(qn + (size_t)dd * D + m * 4);
            float pr = acc[0][reg] * (float)q4[0] + acc[1][reg] * (float)q4[1]
                     + acc[2][reg] * (float)q4[2] + acc[3][reg] * (float)q4[3];
#pragma unroll
            for (int d = 8; d; d >>= 1) pr += __shfl_xor(pr, d, 64);
            p4[reg] = pr;
        }
        // write: shuffle src/pos from already-loaded strip meta (all lanes shuffle, m<4 write)
        int wsrc = __shfl(sC, quad * 4 + (m & 3), 64);
        int wpos = __shfl(pC, quad * 4 + (m & 3), 64);
        float wval = ((m & 3) == 0) ? p4[0] : ((m & 3) == 1) ? p4[1] : ((m & 3) == 2) ? p4[2] : p4[3];
        if (m < 4) {
            int idx = base + quad * 4 + m;
            if (idx < cnt) {
                int2 rc;
                rc.x = __float_as_int(wval * scale);
                rc.y = (wsrc << 3) | r;                     // V2 row id
                rec[wpos] = rc;
            }
        }
        // rotate pipeline
        if (hN) {
            A0 = A0n; A1 = A1n;
            sC = sN; dC = dN; pC = pN;
            sN = sNN; dN = dNN; pN = pNN;
        }
    }
}

// ---------------- fused per-dst softmax+aggregation + output transform ----------------
// grid (AGG_XB, T), 256 threads = 16 quads = 16 same-type nodes per strip.
__global__ void agg_out_kernel(const int* __restrict__ offs, const int2* __restrict__ rec,
                               const _Float16* __restrict__ V2,
                               const float* __restrict__ Wa, const float* __restrict__ skp,
                               const int* __restrict__ toff, const int* __restrict__ nidx,
                               float* __restrict__ out) {
    const int t = blockIdx.y;
    const int beg = toff[t], end = toff[t + 1], cnt = end - beg;
    if (cnt <= 0) return;
    const int nstrips = (cnt + 15) >> 4;
    const int lane = threadIdx.x & 63;
    const int wv = threadIdx.x >> 6;          // 4 waves
    const int quad = lane >> 4, ql = lane & 15;
    const int q16 = wv * 4 + quad;            // node slot 0..15
    const int qb = quad << 4;
    const int m = lane & 15, qd = lane >> 4;  // MFMA roles
    const float sg = 1.f / (1.f + __expf(-skp[t]));

    __shared__ float As[16][68];              // padded stride breaks LDS bank conflicts

    // per-wave B slice (c = wv): canonical cols (scalar f32 out stores stay coalesced)
    bf16x8 Bh2[2], Bl2[2];
    const float* W = Wa + (size_t)t * 4096;
#pragma unroll
    for (int ks = 0; ks < 2; ++ks) load_B_split(W, ks, wv, lane, Bh2[ks], Bl2[ks]);

    for (int s = blockIdx.x; s < nstrips; s += gridDim.x) {
        int base = beg + s * 16;
        int rr = base + q16; if (rr > end - 1) rr = end - 1;   // tail: duplicate last node
        int i = nidx[rr];
        // ---- aggregation for node i (one quad) ----
        const int ebeg = offs[i], eend = offs[i + 1];
        float mmax = -INFINITY, lsum = 0.f;
        float a0 = 0.f, a1 = 0.f, a2 = 0.f, a3 = 0.f;
        for (int cs = ebeg; cs < eend; cs += 16) {
            int cl = eend - cs; if (cl > 16) cl = 16;
            int2 rc; rc.y = 0;
            float sc = -INFINITY;
            if (ql < cl) { rc = rec[cs + ql]; sc = __int_as_float(rc.x); }
            float cm = sc;
#pragma unroll
            for (int d = 8; d; d >>= 1) cm = fmaxf(cm, __shfl_xor(cm, d, 64));
            float mn = fmaxf(mmax, cm);
            float cf = __expf(mmax - mn);
            float ex = (ql < cl) ? __expf(sc - mn) : 0.f;
            float csum = ex;
#pragma unroll
            for (int d = 8; d; d >>= 1) csum += __shfl_xor(csum, d, 64);
            lsum = lsum * cf + csum;
            a0 *= cf; a1 *= cf; a2 *= cf; a3 *= cf;
            for (int e = 0; e < cl; e += 4) {
                float w0 = __shfl(ex, qb + e, 64),     w1 = __shfl(ex, qb + e + 1, 64);
                float w2 = __shfl(ex, qb + e + 2, 64), w3 = __shfl(ex, qb + e + 3, 64);
                int   i0 = __shfl(rc.y, qb + e, 64),     i1 = __shfl(rc.y, qb + e + 1, 64);
                int   i2 = __shfl(rc.y, qb + e + 2, 64), i3 = __shfl(rc.y, qb + e + 3, 64);
                f16x4 v0 = *(const f16x4*)(V2 + (size_t)i0 * D + ql * 4);
                f16x4 v1 = *(const f16x4*)(V2 + (size_t)i1 * D + ql * 4);
                f16x4 v2 = *(const f16x4*)(V2 + (size_t)i2 * D + ql * 4);
                f16x4 v3 = *(const f16x4*)(V2 + (size_t)i3 * D + ql * 4);
                a0 += w0 * (float)v0[0] + w1 * (float)v1[0] + w2 * (float)v2[0] + w3 * (float)v3[0];
                a1 += w0 * (float)v0[1] + w1 * (float)v1[1] + w2 * (float)v2[1] + w3 * (float)v3[1];
                a2 += w0 * (float)v0[2] + w1 * (float)v1[2] + w2 * (float)v2[2] + w3 * (float)v3[2];
                a3 += w0 * (float)v0[3] + w1 * (float)v1[3] + w2 * (float)v2[3] + w3 * (float)v3[3];
            }
            mmax = mn;
        }
        float inv = 1.f / (lsum + 1e-16f);
        As[q16][ql * 4 + 0] = a0 * inv;
        As[q16][ql * 4 + 1] = a1 * inv;
        As[q16][ql * 4 + 2] = a2 * inv;
        As[q16][ql * 4 + 3] = a3 * inv;
        __syncthreads();

        // ---- out transform: each wave computes its 16-col slice (identical MFMA seq) ----
        bf16x8 A0h, A0l, A1h, A1l;
        load_A_split(&As[m][qd * 8], A0h, A0l);
        load_A_split(&As[m][32 + qd * 8], A1h, A1l);
        f32x4 acc = (f32x4){0.f, 0.f, 0.f, 0.f};
        acc = MFMA16(A0h, Bh2[0], acc);
        acc = MFMA16(A0l, Bh2[0], acc);
        acc = MFMA16(A0h, Bl2[0], acc);
        acc = MFMA16(A1h, Bh2[1], acc);
        acc = MFMA16(A1l, Bh2[1], acc);
        acc = MFMA16(A1h, Bl2[1], acc);
#pragma unroll
        for (int reg = 0; reg < 4; ++reg) {
            int rrr = base + qd * 4 + reg;
            if (rrr < end)
                out[(size_t)nidx[rrr] * D + wv * 16 + m] = acc[reg] * sg;
        }
        __syncthreads();   // protect As before next strip
    }
}

// ---------------- launch ----------------
extern "C" void kernel_launch(void* const* d_in, const int* in_sizes, int n_in,
                              void* d_out, int out_size, void* d_ws, size_t ws_size,
                              hipStream_t stream) {
    const float* h     = (const float*)d_in[0];
    const int*   adj   = (const int*)d_in[1];     // [2,E]: src row then dst row
    const int*   etype = (const int*)d_in[2];
    const int*   ntype = (const int*)d_in[3];
    const float* Wk    = (const float*)d_in[6];
    const float* Wq    = (const float*)d_in[7];
    const float* Wv    = (const float*)d_in[8];
    const float* Wa    = (const float*)d_in[9];
    const float* pri   = (const float*)d_in[10];
    const float* Aatt  = (const float*)d_in[11];
    const float* Amsg  = (const float*)d_in[12];
    const float* skp   = (const float*)d_in[13];
    const int N = in_sizes[3];
    const int E = in_sizes[2];
    float* out = (float*)d_out;

    char* w = (char*)d_ws;
    auto alloc = [&](size_t b) { char* p = w; w += (b + 255) & ~(size_t)255; return p; };
    _Float16* kh16 = (_Float16*)alloc((size_t)N * D * 2);
    _Float16* qn   = (_Float16*)alloc((size_t)N * D * 2);
    _Float16* vn   = (_Float16*)alloc((size_t)N * D * 2);
    _Float16* V2   = (_Float16*)alloc((size_t)N * RR * D * 2);
    int* deg  = (int*)alloc((size_t)(N + 16) * 4);
    int* tcnt = deg + N;
    int* rcnt = deg + N + 8;
    int* offs = (int*)alloc((size_t)(N + 1) * 4);
    int* erank = (int*)alloc((size_t)E * 4);
    int* toff = (int*)alloc(64);
    int* tcur = (int*)alloc(64);
    int* roff = (int*)alloc(64);
    int* rcur = (int*)alloc(64);
    int2* rec = (int2*)alloc((size_t)E * 8);
    int* rsrc  = (int*)alloc((size_t)E * 4);
    int* rdst  = (int*)alloc((size_t)E * 4);
    int* rdpos = (int*)alloc((size_t)E * 4);
    int* nidx  = (int*)alloc((size_t)N * 4);
    const int nsb = (N + SCAN_ELEMS - 1) / SCAN_ELEMS;
    int* bsum  = (int*)alloc((size_t)nsb * 4);

    (void)hipMemsetAsync(deg, 0, (size_t)(N + 16) * 4, stream);

    const int mx = (E > N ? E : N);
    const int histBlocks = (mx + 256 * HIST_CH - 1) / (256 * HIST_CH);
    hist_kernel<<<histBlocks, 256, 0, stream>>>(adj + E, etype, ntype, deg, tcnt, rcnt, erank, N, E);
    scan_sum_kernel<<<nsb, SCAN_TPB, 0, stream>>>(deg, bsum, N);
    scan_out_kernel<<<nsb, SCAN_TPB, 0, stream>>>(deg, bsum, nsb, offs, N, E,
                                                  tcnt, toff, tcur, rcnt, roff, rcur);
    const int scatBlocks = (mx + 256 * SCAT_CH - 1) / (256 * SCAT_CH);
    scatter_kernel<<<scatBlocks, 256, 0, stream>>>(adj, adj + E, etype, ntype,
                                                   offs, erank, tcur, rcur,
                                                   rsrc, rdst, rdpos, nidx, N, E);
    proj_kernel<<<dim3(128, 3, TT), 64, 0, stream>>>(h, Wk, Wq, Wv, toff, nidx, kh16, qn, vn);
    score_v2_kernel<<<dim3(SCORE_XB + V2_XB, RR), 256, 0, stream>>>(rsrc, rdst, rdpos, roff,
                                                                    kh16, qn, Aatt, pri, rec,
                                                                    vn, Amsg, V2, N);
    agg_out_kernel<<<dim3(AGG_XB, TT), 256, 0, stream>>>(offs, rec, V2, Wa, skp, toff, nidx, out);
}